// Round 1
// baseline (283.002 us; speedup 1.0000x reference)
//
#include <hip/hip_runtime.h>

// STFT: x[16, 262144] fp32, Hann window 2048, hop 512, reflect pad 1024.
// Output: real[16,1025,513] then imag[16,1025,513], fp32, concatenated.
// Strategy: one block per (batch, frame); radix-2 in-place DIT FFT in LDS.

#define N_FFT   2048
#define LOG2N   11
#define HOP     512
#define PAD     1024
#define NBINS   1025
#define NFRAMES 513
#define NBATCH  16
#define TLEN    262144

__global__ __launch_bounds__(256) void stft_fft_kernel(
    const float* __restrict__ x,
    const float* __restrict__ window,
    float* __restrict__ out)
{
    __shared__ float re[N_FFT];
    __shared__ float im[N_FFT];
    __shared__ float twr[N_FFT / 2];
    __shared__ float twi[N_FFT / 2];

    const int f   = blockIdx.x;   // frame
    const int b   = blockIdx.y;   // batch
    const int tid = threadIdx.x;  // 0..255

    // --- twiddle table: w_k = exp(-2*pi*i*k/N), k = 0..1023 ---
    for (int k = tid; k < N_FFT / 2; k += 256) {
        float ang = -6.283185307179586f * (float)k / (float)N_FFT;
        float s, c;
        sincosf(ang, &s, &c);   // precise libm variant (fp32 accuracy matters here)
        twr[k] = c;
        twi[k] = s;
    }

    // --- load frame with reflect padding + window, bit-reversed into LDS ---
    const float* xb = x + (size_t)b * TLEN;
    const int base = f * HOP - PAD;
    for (int n = tid; n < N_FFT; n += 256) {
        int j = base + n;
        if (j < 0)          j = -j;               // reflect left (PAD < TLEN, single reflection)
        else if (j >= TLEN) j = 2 * TLEN - 2 - j; // reflect right
        int r = (int)(__brev((unsigned)n) >> (32 - LOG2N));
        re[r] = xb[j] * window[n];
        im[r] = 0.0f;
    }
    __syncthreads();

    // --- 11 radix-2 DIT stages, in-place ---
    for (int s = 1; s <= LOG2N; ++s) {
        const int len      = 1 << s;
        const int half     = len >> 1;
        const int tw_shift = LOG2N - s;
        for (int t = tid; t < N_FFT / 2; t += 256) {
            const int pos = t & (half - 1);
            const int i   = ((t >> (s - 1)) << s) + pos;
            const int j   = i + half;
            const int tw  = pos << tw_shift;
            const float wr = twr[tw], wi = twi[tw];
            const float xr = re[j],  xi = im[j];
            const float vr = xr * wr - xi * wi;
            const float vi = xr * wi + xi * wr;
            const float ur = re[i],  ui = im[i];
            re[i] = ur + vr;  im[i] = ui + vi;
            re[j] = ur - vr;  im[j] = ui - vi;
        }
        __syncthreads();
    }

    // --- write bins 0..1024: out[b, k, f], real block then imag block ---
    const size_t half_out = (size_t)NBATCH * NBINS * NFRAMES;  // 8,413,200
    float* __restrict__ outr = out;
    float* __restrict__ outi = out + half_out;
    for (int k = tid; k < NBINS; k += 256) {
        const size_t o = ((size_t)b * NBINS + (size_t)k) * NFRAMES + (size_t)f;
        outr[o] = re[k];
        outi[o] = im[k];
    }
}

extern "C" void kernel_launch(void* const* d_in, const int* in_sizes, int n_in,
                              void* d_out, int out_size, void* d_ws, size_t ws_size,
                              hipStream_t stream) {
    const float* x      = (const float*)d_in[0];
    const float* window = (const float*)d_in[1];
    float* out          = (float*)d_out;

    dim3 grid(NFRAMES, NBATCH);  // 513 x 16 = 8208 blocks
    stft_fft_kernel<<<grid, 256, 0, stream>>>(x, window, out);
}

// Round 2
// 266.481 us; speedup vs baseline: 1.0620x; 1.0620x over previous
//
#include <hip/hip_runtime.h>

// STFT: x[16, 262144] fp32, Hann window 2048, hop 512, reflect pad 1024.
// Output: real[16,1025,513] then imag[16,1025,513], fp32, concatenated.
//
// Round 2:
//  - LDS index padding a -> a + (a>>5): kills the 64-way bank conflict of the
//    bit-reversed store (stride-32 -> stride-33) and stage-1..5 4-way conflicts.
//  - Twiddles computed once per launch by a tiny init kernel (was 8208x1024 sincosf).
//  - Spectrum staged to d_ws in [b,f,k] (frame-contiguous, coalesced) then
//    transposed to [b,k,f] with a 32x32 LDS tile kernel (coalesced both ways).
//    Fallback to direct scattered write if ws_size is too small.

#define N_FFT   2048
#define LOG2N   11
#define HOP     512
#define PADL    1024
#define NBINS   1025
#define NFRAMES 513
#define NBATCH  16
#define TLEN    262144

#define HALF_OUT  ((size_t)NBATCH * NBINS * NFRAMES)   // 8,413,200 floats per (real|imag)
#define SPEC_HALF ((size_t)NBATCH * NFRAMES * NBINS)   // same count, [b,f,k] layout
#define TW_FLOATS 2048                                  // twr[1024] ++ twi[1024]

// padded LDS index: breaks power-of-2 bank aliasing (32 banks)
__device__ __forceinline__ int pidx(int a) { return a + (a >> 5); }

__global__ __launch_bounds__(256) void twiddle_init(float* __restrict__ tw) {
    int k = blockIdx.x * 256 + threadIdx.x;   // 0..1023
    if (k < N_FFT / 2) {
        float s, c;
        sincosf(-6.283185307179586f * (float)k / (float)N_FFT, &s, &c);
        tw[k]        = c;
        tw[1024 + k] = s;
    }
}

template <bool STAGED>
__global__ __launch_bounds__(256) void stft_fft_kernel(
    const float* __restrict__ x,
    const float* __restrict__ window,
    const float* __restrict__ twg,   // [2048] precomputed (STAGED only)
    float* __restrict__ dst)         // STAGED: spec [2][b][f][k]; else: out [2][b][k][f]
{
    __shared__ float re[2112];       // pidx(2047) = 2110
    __shared__ float im[2112];
    __shared__ float twr[N_FFT / 2];
    __shared__ float twi[N_FFT / 2];

    const int f   = blockIdx.x;
    const int b   = blockIdx.y;
    const int tid = threadIdx.x;

    if (STAGED) {
        for (int k = tid; k < N_FFT / 2; k += 256) {
            twr[k] = twg[k];
            twi[k] = twg[1024 + k];
        }
    } else {
        for (int k = tid; k < N_FFT / 2; k += 256) {
            float s, c;
            sincosf(-6.283185307179586f * (float)k / (float)N_FFT, &s, &c);
            twr[k] = c;
            twi[k] = s;
        }
    }

    // load frame with reflect padding + window, bit-reversed into padded LDS
    const float* xb = x + (size_t)b * TLEN;
    const int base = f * HOP - PADL;
    for (int n = tid; n < N_FFT; n += 256) {
        int j = base + n;
        if (j < 0)          j = -j;
        else if (j >= TLEN) j = 2 * TLEN - 2 - j;
        int r  = (int)(__brev((unsigned)n) >> (32 - LOG2N));
        int pr = pidx(r);
        re[pr] = xb[j] * window[n];
        im[pr] = 0.0f;
    }
    __syncthreads();

    // 11 radix-2 DIT stages, in-place, padded indices
    for (int s = 1; s <= LOG2N; ++s) {
        const int half     = 1 << (s - 1);
        const int tw_shift = LOG2N - s;
        for (int t = tid; t < N_FFT / 2; t += 256) {
            const int pos = t & (half - 1);
            const int i   = ((t >> (s - 1)) << s) + pos;
            const int j   = i + half;
            const int pi  = pidx(i), pj = pidx(j);
            const int tw  = pos << tw_shift;
            const float wr = twr[tw], wi = twi[tw];
            const float xr = re[pj],  xi = im[pj];
            const float vr = fmaf(xr, wr, -xi * wi);
            const float vi = fmaf(xr, wi,  xi * wr);
            const float ur = re[pi],  ui = im[pi];
            re[pi] = ur + vr;  im[pi] = ui + vi;
            re[pj] = ur - vr;  im[pj] = ui - vi;
        }
        __syncthreads();
    }

    if (STAGED) {
        // frame-contiguous: spec[b][f][k], fully coalesced 1025-float rows
        const size_t o = (size_t)(b * NFRAMES + f) * NBINS;
        for (int k = tid; k < NBINS; k += 256) {
            dst[o + k]             = re[pidx(k)];
            dst[SPEC_HALF + o + k] = im[pidx(k)];
        }
    } else {
        // fallback: direct scattered write (round-1 behavior)
        for (int k = tid; k < NBINS; k += 256) {
            const size_t o = ((size_t)b * NBINS + (size_t)k) * NFRAMES + (size_t)f;
            dst[o]            = re[pidx(k)];
            dst[HALF_OUT + o] = im[pidx(k)];
        }
    }
}

// [b,f,k] -> [b,k,f] transpose, 32x32 LDS tiles, coalesced both directions
__global__ __launch_bounds__(256) void transpose_kernel(
    const float* __restrict__ spec,
    float* __restrict__ out)
{
    __shared__ float tile[32][33];
    const int kt   = blockIdx.x;           // 0..32  (k tiles)
    const int ft   = blockIdx.y;           // 0..16  (f tiles)
    const int z    = blockIdx.z;           // 0..31 = half*16 + b
    const int half = z >> 4, b = z & 15;

    const float* in = spec + (size_t)half * SPEC_HALF + (size_t)b * NFRAMES * NBINS;
    float*       op = out  + (size_t)half * HALF_OUT  + (size_t)b * NBINS * NFRAMES;

    const int tx = threadIdx.x & 31;
    const int ty = threadIdx.x >> 5;       // 0..7
    const int k0 = kt * 32, f0 = ft * 32;

#pragma unroll
    for (int i = 0; i < 4; ++i) {
        const int fr = f0 + ty + i * 8;
        const int kc = k0 + tx;
        tile[ty + i * 8][tx] =
            (fr < NFRAMES && kc < NBINS) ? in[(size_t)fr * NBINS + kc] : 0.0f;
    }
    __syncthreads();
#pragma unroll
    for (int i = 0; i < 4; ++i) {
        const int kr = k0 + ty + i * 8;
        const int fc = f0 + tx;
        if (kr < NBINS && fc < NFRAMES)
            op[(size_t)kr * NFRAMES + fc] = tile[tx][ty + i * 8];
    }
}

extern "C" void kernel_launch(void* const* d_in, const int* in_sizes, int n_in,
                              void* d_out, int out_size, void* d_ws, size_t ws_size,
                              hipStream_t stream) {
    const float* x      = (const float*)d_in[0];
    const float* window = (const float*)d_in[1];
    float* out          = (float*)d_out;

    const size_t need = ((size_t)TW_FLOATS + 2 * SPEC_HALF) * sizeof(float);
    dim3 gfft(NFRAMES, NBATCH);   // 513 x 16 = 8208 blocks

    if (ws_size >= need) {
        float* tw   = (float*)d_ws;
        float* spec = tw + TW_FLOATS;
        twiddle_init<<<4, 256, 0, stream>>>(tw);
        stft_fft_kernel<true><<<gfft, 256, 0, stream>>>(x, window, tw, spec);
        dim3 gt(33, 17, 32);      // ceil(1025/32) x ceil(513/32) x (16 b * 2 halves)
        transpose_kernel<<<gt, 256, 0, stream>>>(spec, out);
    } else {
        stft_fft_kernel<false><<<gfft, 256, 0, stream>>>(x, window, nullptr, out);
    }
}

// Round 3
// 161.233 us; speedup vs baseline: 1.7552x; 1.6528x over previous
//
#include <hip/hip_runtime.h>

// STFT: x[16, 262144] fp32, Hann 2048, hop 512, reflect pad 1024.
// Output: real[16,1025,513] ++ imag[16,1025,513], fp32.
//
// Round 3:
//  - Pack TWO real frames into ONE complex 2048-FFT (z = a + i*b), unpack via
//    conjugate symmetry. Halves FFT blocks (8208 -> 4112) and LDS traffic.
//  - Per-stage contiguous twiddle tables tw[half + pos]: stride-1 lane access
//    (conflict-free) instead of stride-2^k (which put stages 3..10 entirely in
//    bank 0 -> up to 32-way serialization; the remaining 5.3e7 conflicts).
//  - Data in LDS as float2 (b64 ops, half the LDS instruction count), padded
//    index a + (a>>5) to keep the bit-reversal scatter conflict-free.

#define N_FFT   2048
#define LOG2N   11
#define HOP     512
#define PADL    1024
#define NBINS   1025
#define NFRAMES 513
#define NBATCH  16
#define TLEN    262144

#define HALF_OUT  ((size_t)NBATCH * NBINS * NFRAMES)   // 8,413,200 floats
#define SPEC_HALF HALF_OUT                              // staging, [b,f,k]
#define TW_COUNT  2048                                  // per-stage tables, float2

__device__ __forceinline__ int pidx(int a) { return a + (a >> 5); }

__device__ __forceinline__ int refl(int j) {
    if (j < 0)          j = -j;
    else if (j >= TLEN) j = 2 * TLEN - 2 - j;
    return j;
}

// tw[half + pos] = exp(-i*pi*pos/half), for half = 1,2,4,...,1024
__global__ __launch_bounds__(256) void twiddle_init(float2* __restrict__ tw) {
    int idx = blockIdx.x * 256 + threadIdx.x;
    if (idx >= TW_COUNT) return;
    int half = (idx == 0) ? 1 : (1 << (31 - __clz(idx)));
    int pos  = (idx == 0) ? 0 : idx - half;
    float s, c;
    sincosf(-3.14159265358979323f * (float)pos / (float)half, &s, &c);
    tw[idx] = make_float2(c, s);
}

template <bool STAGED>
__global__ __launch_bounds__(256) void stft_fft2(
    const float* __restrict__ x,
    const float* __restrict__ window,
    const float2* __restrict__ twg,   // [2048] per-stage twiddles (STAGED)
    float* __restrict__ dst)          // STAGED: spec[2][b][f][k]; else out[2][b][k][f]
{
    __shared__ float2 z[2112];        // pidx(2047)=2110, float2
    __shared__ float2 tws[TW_COUNT];

    const int g   = blockIdx.x;       // frame pair
    const int b   = blockIdx.y;
    const int tid = threadIdx.x;
    const int fa  = 2 * g;
    const bool hasb = (2 * g + 1) < NFRAMES;
    const int fb  = hasb ? (2 * g + 1) : fa;

    if (STAGED) {
        const float4* s4 = (const float4*)twg;
        float4* d4 = (float4*)tws;
        for (int i = tid; i < TW_COUNT / 2; i += 256) d4[i] = s4[i];
    } else {
        for (int idx = tid; idx < TW_COUNT; idx += 256) {
            int half = (idx == 0) ? 1 : (1 << (31 - __clz(idx)));
            int pos  = (idx == 0) ? 0 : idx - half;
            float s, c;
            sincosf(-3.14159265358979323f * (float)pos / (float)half, &s, &c);
            tws[idx] = make_float2(c, s);
        }
    }

    // load both frames (windowed) into one complex sequence, bit-reversed
    const float* xb = x + (size_t)b * TLEN;
    const int basea = fa * HOP - PADL;
    const int baseb = fb * HOP - PADL;
    for (int n = tid; n < N_FFT; n += 256) {
        const float w  = window[n];
        const float va = xb[refl(basea + n)] * w;
        const float vb = xb[refl(baseb + n)] * w;
        const int r = (int)(__brev((unsigned)n) >> (32 - LOG2N));
        z[pidx(r)] = make_float2(va, vb);
    }
    __syncthreads();

    // 11 radix-2 DIT stages; twiddle at tw[half+pos] (stride-1 lane access)
    for (int s = 1; s <= LOG2N; ++s) {
        const int half = 1 << (s - 1);
        for (int t = tid; t < N_FFT / 2; t += 256) {
            const int pos = t & (half - 1);
            const int i   = ((t >> (s - 1)) << s) + pos;
            const int j   = i + half;
            const float2 w  = tws[half + pos];
            const float2 zj = z[pidx(j)];
            const float2 zi = z[pidx(i)];
            const float vr = fmaf(zj.x, w.x, -zj.y * w.y);
            const float vi = fmaf(zj.x, w.y,  zj.y * w.x);
            z[pidx(i)] = make_float2(zi.x + vr, zi.y + vi);
            z[pidx(j)] = make_float2(zi.x - vr, zi.y - vi);
        }
        __syncthreads();
    }

    // unpack two real spectra: A = (Z[k]+conj(Z[N-k]))/2, B = (Z[k]-conj(Z[N-k]))/2i
    for (int k = tid; k < NBINS; k += 256) {
        const float2 zk = z[pidx(k)];
        const float2 zr = z[pidx((N_FFT - k) & (N_FFT - 1))];
        const float ar = 0.5f * (zk.x + zr.x);
        const float ai = 0.5f * (zk.y - zr.y);
        const float br = 0.5f * (zk.y + zr.y);
        const float bi = 0.5f * (zr.x - zk.x);
        if (STAGED) {
            float* dr = dst;
            float* di = dst + SPEC_HALF;
            const size_t oa = ((size_t)b * NFRAMES + fa) * NBINS + k;
            dr[oa] = ar;  di[oa] = ai;
            if (hasb) {
                const size_t ob = ((size_t)b * NFRAMES + fb) * NBINS + k;
                dr[ob] = br;  di[ob] = bi;
            }
        } else {
            float* dr = dst;
            float* di = dst + HALF_OUT;
            const size_t oa = ((size_t)b * NBINS + k) * NFRAMES + fa;
            dr[oa] = ar;  di[oa] = ai;
            if (hasb) {
                dr[oa + 1] = br;  di[oa + 1] = bi;
            }
        }
    }
}

// [b,f,k] -> [b,k,f] transpose, 32x32 LDS tiles, coalesced both directions
__global__ __launch_bounds__(256) void transpose_kernel(
    const float* __restrict__ spec,
    float* __restrict__ out)
{
    __shared__ float tile[32][33];
    const int kt   = blockIdx.x;
    const int ft   = blockIdx.y;
    const int z    = blockIdx.z;           // half*16 + b
    const int half = z >> 4, b = z & 15;

    const float* in = spec + (size_t)half * SPEC_HALF + (size_t)b * NFRAMES * NBINS;
    float*       op = out  + (size_t)half * HALF_OUT  + (size_t)b * NBINS * NFRAMES;

    const int tx = threadIdx.x & 31;
    const int ty = threadIdx.x >> 5;
    const int k0 = kt * 32, f0 = ft * 32;

#pragma unroll
    for (int i = 0; i < 4; ++i) {
        const int fr = f0 + ty + i * 8;
        const int kc = k0 + tx;
        tile[ty + i * 8][tx] =
            (fr < NFRAMES && kc < NBINS) ? in[(size_t)fr * NBINS + kc] : 0.0f;
    }
    __syncthreads();
#pragma unroll
    for (int i = 0; i < 4; ++i) {
        const int kr = k0 + ty + i * 8;
        const int fc = f0 + tx;
        if (kr < NBINS && fc < NFRAMES)
            op[(size_t)kr * NFRAMES + fc] = tile[tx][ty + i * 8];
    }
}

extern "C" void kernel_launch(void* const* d_in, const int* in_sizes, int n_in,
                              void* d_out, int out_size, void* d_ws, size_t ws_size,
                              hipStream_t stream) {
    const float* x      = (const float*)d_in[0];
    const float* window = (const float*)d_in[1];
    float* out          = (float*)d_out;

    const size_t need = TW_COUNT * sizeof(float2) + 2 * SPEC_HALF * sizeof(float);
    dim3 gfft((NFRAMES + 1) / 2, NBATCH);   // 257 x 16 = 4112 blocks

    if (ws_size >= need) {
        float2* tw  = (float2*)d_ws;
        float*  spec = (float*)(tw + TW_COUNT);
        twiddle_init<<<8, 256, 0, stream>>>(tw);
        stft_fft2<true><<<gfft, 256, 0, stream>>>(x, window, tw, spec);
        dim3 gt(33, 17, 32);
        transpose_kernel<<<gt, 256, 0, stream>>>(spec, out);
    } else {
        stft_fft2<false><<<gfft, 256, 0, stream>>>(x, window, nullptr, out);
    }
}